// Round 1
// baseline (99.267 us; speedup 1.0000x reference)
//
#include <hip/hip_runtime.h>
#include <hip/hip_bf16.h>

#define NB 8
#define NN 512
#define NS 64
#define NH 16
#define ND 256

typedef __attribute__((ext_vector_type(8))) short bf16x8;
typedef __attribute__((ext_vector_type(4))) short bf16x4;
typedef __attribute__((ext_vector_type(4))) float f32x4;

__device__ inline float wred(float v) {
#pragma unroll
  for (int m = 32; m; m >>= 1) v += __shfl_xor(v, m, 64);
  return v;
}

// ---- gather: spb[b][n][s][h] = (pos==0) ? 0 : emb[pos][h], stored bf16.
// Flat [B,N,S,H] buffer reinterpreted later as [B,H,N,S] (torch .view semantics).
__global__ __launch_bounds__(256) void k_gather(const int* __restrict__ pos,
                                                const float* __restrict__ emb,
                                                __hip_bfloat16* __restrict__ spb) {
  int t = blockIdx.x * 256 + threadIdx.x;      // [0, NB*NN*NS*NH)
  int h = t & (NH - 1);
  int bns = t >> 4;
  int idx = pos[bns];
  float v = (idx == 0) ? 0.0f : emb[idx * NH + h];
  spb[t] = __float2bfloat16(v);
}

// ---- per-row of A: rdeg = rsqrt(sum), plus A cast to bf16
__global__ __launch_bounds__(256) void k_rowA(const float* __restrict__ A,
                                              __hip_bfloat16* __restrict__ Ab,
                                              float* __restrict__ rdeg) {
  int wave = threadIdx.x >> 6, lane = threadIdx.x & 63;
  int row = blockIdx.x * 4 + wave;             // [0, NB*NN)
  const float* ar = A + (size_t)row * NN;
  float4 v0 = *(const float4*)(ar + lane * 8);
  float4 v1 = *(const float4*)(ar + lane * 8 + 4);
  float s = v0.x + v0.y + v0.z + v0.w + v1.x + v1.y + v1.z + v1.w;
  union { bf16x8 v; __hip_bfloat16 h[8]; } u;
  u.h[0] = __float2bfloat16(v0.x); u.h[1] = __float2bfloat16(v0.y);
  u.h[2] = __float2bfloat16(v0.z); u.h[3] = __float2bfloat16(v0.w);
  u.h[4] = __float2bfloat16(v1.x); u.h[5] = __float2bfloat16(v1.y);
  u.h[6] = __float2bfloat16(v1.z); u.h[7] = __float2bfloat16(v1.w);
  *(bf16x8*)(void*)(Ab + (size_t)row * NN + lane * 8) = u.v;
  s = wred(s);
  if (lane == 0) rdeg[row] = rsqrtf(s);
}

// ---- per-row of H: Hb (bf16, same layout), HT (bf16 transpose per batch), h2
__global__ __launch_bounds__(256) void k_rowH(const float* __restrict__ H,
                                              __hip_bfloat16* __restrict__ Hb,
                                              __hip_bfloat16* __restrict__ HT,
                                              float* __restrict__ h2) {
  int wave = threadIdx.x >> 6, lane = threadIdx.x & 63;
  int row = blockIdx.x * 4 + wave;             // row = b*NN + n
  int b = row >> 9, n = row & (NN - 1);
  const float* hr = H + (size_t)row * ND;
  float4 v = *(const float4*)(hr + lane * 4);
  float ss = v.x * v.x + v.y * v.y + v.z * v.z + v.w * v.w;
  union { bf16x4 v4; __hip_bfloat16 h[4]; } u;
  u.h[0] = __float2bfloat16(v.x); u.h[1] = __float2bfloat16(v.y);
  u.h[2] = __float2bfloat16(v.z); u.h[3] = __float2bfloat16(v.w);
  *(bf16x4*)(void*)(Hb + (size_t)row * ND + lane * 4) = u.v4;
  __hip_bfloat16* tp = HT + ((size_t)b * ND + lane * 4) * NN + n;
  tp[0 * NN] = u.h[0]; tp[1 * NN] = u.h[1]; tp[2 * NN] = u.h[2]; tp[3 * NN] = u.h[3];
  ss = wred(ss);
  if (lane == 0) h2[row] = ss;
}

// ---- m2 from bf16 M
__global__ __launch_bounds__(256) void k_m2(const __hip_bfloat16* __restrict__ Mb,
                                            float* __restrict__ m2) {
  int wave = threadIdx.x >> 6, lane = threadIdx.x & 63;
  int row = blockIdx.x * 4 + wave;
  union { bf16x4 v4; __hip_bfloat16 h[4]; } u;
  u.v4 = *(const bf16x4*)(const void*)(Mb + (size_t)row * ND + lane * 4);
  float ss = 0.f;
#pragma unroll
  for (int i = 0; i < 4; ++i) { float f = __bfloat162float(u.h[i]); ss += f * f; }
  ss = wred(ss);
  if (lane == 0) m2[row] = ss;
}

// ---- one wave computes a 64x64 tile of C = X * Y^T (rows of X vs rows of Y).
// A- and B-fragments use the IDENTICAL (row, k) load formula -> result is
// invariant to the intra-lane k ordering (A/B layouts are mirror-symmetric).
template<int K>
__device__ inline void wave_xyt(const __hip_bfloat16* __restrict__ X, int ldx,
                                const __hip_bfloat16* __restrict__ Y, int ldy,
                                int r0, int c0, int lane, f32x4 acc[4][4]) {
  int rl = lane & 15, g = lane >> 4;
#pragma unroll
  for (int kk = 0; kk < K / 32; ++kk) {
    int kb = kk * 32 + g * 8;
    bf16x8 a[4], bv[4];
#pragma unroll
    for (int i = 0; i < 4; ++i)
      a[i] = *(const bf16x8*)(const void*)(X + (size_t)(r0 + i * 16 + rl) * ldx + kb);
#pragma unroll
    for (int j = 0; j < 4; ++j)
      bv[j] = *(const bf16x8*)(const void*)(Y + (size_t)(c0 + j * 16 + rl) * ldy + kb);
#pragma unroll
    for (int i = 0; i < 4; ++i)
#pragma unroll
      for (int j = 0; j < 4; ++j)
        acc[i][j] = __builtin_amdgcn_mfma_f32_16x16x32_bf16(a[i], bv[j], acc[i][j], 0, 0, 0);
  }
}

__device__ inline void zero_acc(f32x4 acc[4][4]) {
#pragma unroll
  for (int i = 0; i < 4; ++i)
#pragma unroll
    for (int j = 0; j < 4; ++j) {
      acc[i][j][0] = 0.f; acc[i][j][1] = 0.f; acc[i][j][2] = 0.f; acc[i][j][3] = 0.f;
    }
}

// ---- M = rdeg ⊙ (A·H):  C[n][d] = sum_m Ab[n][m] * HT[d][m]
__global__ __launch_bounds__(256) void k_gemmM(const __hip_bfloat16* __restrict__ Ab,
                                               const __hip_bfloat16* __restrict__ HT,
                                               const float* __restrict__ rdeg,
                                               __hip_bfloat16* __restrict__ Mb) {
  int wave = threadIdx.x >> 6, lane = threadIdx.x & 63;
  int tile = blockIdx.x * 4 + wave;            // [0, NB * 8 * 4)
  int b = tile >> 5, t = tile & 31;
  int r0 = (t >> 2) * 64, c0 = (t & 3) * 64;
  f32x4 acc[4][4];
  zero_acc(acc);
  wave_xyt<NN>(Ab + (size_t)b * NN * NN, NN, HT + (size_t)b * ND * NN, NN, r0, c0, lane, acc);
  int rl = lane & 15, g = lane >> 4;
#pragma unroll
  for (int i = 0; i < 4; ++i)
#pragma unroll
    for (int j = 0; j < 4; ++j)
#pragma unroll
      for (int r = 0; r < 4; ++r) {
        int row = r0 + i * 16 + g * 4 + r;
        int col = c0 + j * 16 + rl;
        float m = rdeg[b * NN + row] * acc[i][j][r];
        Mb[((size_t)b * NN + row) * ND + col] = __float2bfloat16(m);
      }
}

// ---- G[b][n][m] = exp(-(h2[n] + m2[m] - 2*H[n]·M[m]) / (2 sigma^2))
__global__ __launch_bounds__(256) void k_gauss(const __hip_bfloat16* __restrict__ Hb,
                                               const __hip_bfloat16* __restrict__ Mb,
                                               const float* __restrict__ h2,
                                               const float* __restrict__ m2,
                                               const float* __restrict__ sigma,
                                               float* __restrict__ G) {
  int wave = threadIdx.x >> 6, lane = threadIdx.x & 63;
  int tile = blockIdx.x * 4 + wave;            // [0, NB * 8 * 8)
  int b = tile >> 6, t = tile & 63;
  int r0 = (t >> 3) * 64, c0 = (t & 7) * 64;
  f32x4 acc[4][4];
  zero_acc(acc);
  wave_xyt<ND>(Hb + (size_t)b * NN * ND, ND, Mb + (size_t)b * NN * ND, ND, r0, c0, lane, acc);
  float sg = sigma[0];
  float inv = 0.5f / (sg * sg);
  int rl = lane & 15, g = lane >> 4;
  float* Gb = G + (size_t)b * NN * NN;
#pragma unroll
  for (int i = 0; i < 4; ++i)
#pragma unroll
    for (int j = 0; j < 4; ++j)
#pragma unroll
      for (int r = 0; r < 4; ++r) {
        int row = r0 + i * 16 + g * 4 + r;
        int col = c0 + j * 16 + rl;
        float d2 = h2[b * NN + row] + m2[b * NN + col] - 2.0f * acc[i][j][r];
        Gb[(size_t)row * NN + col] = __expf(-d2 * inv);
      }
}

// ---- out[b][h][n][m] = Gram(spb[b][h]) + G[b][n][m]
__global__ __launch_bounds__(256) void k_out(const __hip_bfloat16* __restrict__ spb,
                                             const float* __restrict__ G,
                                             float* __restrict__ out) {
  int wave = threadIdx.x >> 6, lane = threadIdx.x & 63;
  int tile = blockIdx.x * 4 + wave;            // [0, NB*NH * 8 * 8)
  int bh = tile >> 6, t = tile & 63;
  int b = bh >> 4;
  int r0 = (t >> 3) * 64, c0 = (t & 7) * 64;
  const __hip_bfloat16* X = spb + (size_t)bh * NN * NS;
  f32x4 acc[4][4];
  zero_acc(acc);
  wave_xyt<NS>(X, NS, X, NS, r0, c0, lane, acc);
  const float* Gb = G + (size_t)b * NN * NN;
  float* ob = out + (size_t)bh * NN * NN;
  int rl = lane & 15, g = lane >> 4;
#pragma unroll
  for (int i = 0; i < 4; ++i)
#pragma unroll
    for (int j = 0; j < 4; ++j)
#pragma unroll
      for (int r = 0; r < 4; ++r) {
        int row = r0 + i * 16 + g * 4 + r;
        int col = c0 + j * 16 + rl;
        ob[(size_t)row * NN + col] = acc[i][j][r] + Gb[(size_t)row * NN + col];
      }
}

extern "C" void kernel_launch(void* const* d_in, const int* in_sizes, int n_in,
                              void* d_out, int out_size, void* d_ws, size_t ws_size,
                              hipStream_t stream) {
  const int* pos = (const int*)d_in[0];
  const float* H = (const float*)d_in[1];
  const float* A = (const float*)d_in[2];
  const float* sigma = (const float*)d_in[3];
  const float* emb = (const float*)d_in[4];
  // d_in[5] (vt_weight) only affects the sliced-off padded row/col -> unused.
  float* out = (float*)d_out;

  char* ws = (char*)d_ws;
  size_t off = 0;
  auto alloc = [&](size_t bytes) -> void* {
    void* p = ws + off;
    off = (off + bytes + 255) & ~(size_t)255;
    return p;
  };
  __hip_bfloat16* spb = (__hip_bfloat16*)alloc((size_t)NB * NH * NN * NS * 2);
  __hip_bfloat16* Ab  = (__hip_bfloat16*)alloc((size_t)NB * NN * NN * 2);
  __hip_bfloat16* Hb  = (__hip_bfloat16*)alloc((size_t)NB * NN * ND * 2);
  __hip_bfloat16* HT  = (__hip_bfloat16*)alloc((size_t)NB * ND * NN * 2);
  __hip_bfloat16* Mb  = (__hip_bfloat16*)alloc((size_t)NB * NN * ND * 2);
  float* G    = (float*)alloc((size_t)NB * NN * NN * 4);
  float* rdeg = (float*)alloc((size_t)NB * NN * 4);
  float* h2   = (float*)alloc((size_t)NB * NN * 4);
  float* m2   = (float*)alloc((size_t)NB * NN * 4);

  k_gather<<<(NB * NN * NS * NH) / 256, 256, 0, stream>>>(pos, emb, spb);
  k_rowA<<<NB * NN / 4, 256, 0, stream>>>(A, Ab, rdeg);
  k_rowH<<<NB * NN / 4, 256, 0, stream>>>(H, Hb, HT, h2);
  k_gemmM<<<NB * (NN / 64) * (ND / 64) / 4, 256, 0, stream>>>(Ab, HT, rdeg, Mb);
  k_m2<<<NB * NN / 4, 256, 0, stream>>>(Mb, m2);
  k_gauss<<<NB * (NN / 64) * (NN / 64) / 4, 256, 0, stream>>>(Hb, Mb, h2, m2, sigma, G);
  k_out<<<NB * NH * (NN / 64) * (NN / 64) / 4, 256, 0, stream>>>(spb, G, out);
}

// Round 3
// 76.050 us; speedup vs baseline: 1.3053x; 1.3053x over previous
//
#include <hip/hip_runtime.h>
#include <hip/hip_bf16.h>

#define NB 8
#define NN 512
#define NS 64
#define NH 16
#define ND 256

typedef __attribute__((ext_vector_type(8))) short bf16x8;
typedef __attribute__((ext_vector_type(4))) short bf16x4;
typedef __attribute__((ext_vector_type(4))) float f32x4;

__device__ inline float wred(float v) {
#pragma unroll
  for (int m = 32; m; m >>= 1) v += __shfl_xor(v, m, 64);
  return v;
}
// reduce across the 16-lane rl group (lanes sharing g4)
__device__ inline float wred16(float v) {
#pragma unroll
  for (int m = 1; m < 16; m <<= 1) v += __shfl_xor(v, m, 64);
  return v;
}
__device__ inline ushort f2bf(float x) {
  __hip_bfloat16 h = __float2bfloat16(x);
  return *(ushort*)&h;
}

// =====================================================================
// K1: prep — grid-partitioned roles:
//   [0,1024)     gather spb  (flat [B,N,S,H], later viewed as [B,H,N,S])
//   [1024,2048)  A rows -> Ab bf16 + rdeg
//   [2048,3072)  H rows -> Hb bf16 + h2
//   [3072,3328)  H -> HT bf16 transpose via LDS 64x64 tiles
// =====================================================================
__global__ __launch_bounds__(256) void k_prep(const int* __restrict__ pos,
                                              const float* __restrict__ emb,
                                              const float* __restrict__ H,
                                              const float* __restrict__ A,
                                              __hip_bfloat16* __restrict__ spb,
                                              __hip_bfloat16* __restrict__ Ab,
                                              __hip_bfloat16* __restrict__ Hb,
                                              __hip_bfloat16* __restrict__ HT,
                                              float* __restrict__ rdeg,
                                              float* __restrict__ h2) {
  __shared__ ushort T[64][68];
  int blk = blockIdx.x, tid = threadIdx.x;
  int wave = tid >> 6, lane = tid & 63;

  if (blk < 1024) {
    // ---- gather: one thread per (b,n,s), writes 16 h-values (32 B)
    int t = blk * 256 + tid;               // [0, NB*NN*NS) = [0, 262144)
    int idx = pos[t];
    __hip_bfloat16* dst = spb + (size_t)t * NH;
    union { bf16x8 v; ushort h[8]; } u0, u1;
    if (idx == 0) {
#pragma unroll
      for (int i = 0; i < 8; ++i) { u0.h[i] = 0; u1.h[i] = 0; }
    } else {
      const float* er = emb + idx * NH;
#pragma unroll
      for (int i = 0; i < 8; ++i) { u0.h[i] = f2bf(er[i]); u1.h[i] = f2bf(er[8 + i]); }
    }
    *(bf16x8*)(void*)dst = u0.v;
    *(bf16x8*)(void*)(dst + 8) = u1.v;
  } else if (blk < 2048) {
    // ---- A rows: bf16 cast + rdeg
    int row = (blk - 1024) * 4 + wave;     // [0, NB*NN)
    const float* ar = A + (size_t)row * NN;
    float4 v0 = *(const float4*)(ar + lane * 8);
    float4 v1 = *(const float4*)(ar + lane * 8 + 4);
    float s = v0.x + v0.y + v0.z + v0.w + v1.x + v1.y + v1.z + v1.w;
    union { bf16x8 v; ushort h[8]; } u;
    u.h[0] = f2bf(v0.x); u.h[1] = f2bf(v0.y); u.h[2] = f2bf(v0.z); u.h[3] = f2bf(v0.w);
    u.h[4] = f2bf(v1.x); u.h[5] = f2bf(v1.y); u.h[6] = f2bf(v1.z); u.h[7] = f2bf(v1.w);
    *(bf16x8*)(void*)(Ab + (size_t)row * NN + lane * 8) = u.v;
    s = wred(s);
    if (lane == 0) rdeg[row] = rsqrtf(s);
  } else if (blk < 3072) {
    // ---- H rows: bf16 cast + h2 (fp32)
    int row = (blk - 2048) * 4 + wave;     // [0, NB*NN)
    const float* hr = H + (size_t)row * ND;
    float4 v = *(const float4*)(hr + lane * 4);
    float ss = v.x * v.x + v.y * v.y + v.z * v.z + v.w * v.w;
    union { bf16x4 v4; ushort h[4]; } u;
    u.h[0] = f2bf(v.x); u.h[1] = f2bf(v.y); u.h[2] = f2bf(v.z); u.h[3] = f2bf(v.w);
    *(bf16x4*)(void*)(Hb + (size_t)row * ND + lane * 4) = u.v4;
    ss = wred(ss);
    if (lane == 0) h2[row] = ss;
  } else {
    // ---- HT transpose: 64(n) x 64(d) tile through LDS, coalesced both sides
    int bi = blk - 3072;                   // [0, 256)
    int b = bi >> 5, r = bi & 31;
    int d0 = (r >> 3) * 64, n0 = (r & 7) * 64;
    int n = tid >> 2, c = (tid & 3) * 16;
    const float* src = H + ((size_t)b * NN + n0 + n) * ND + d0 + c;
#pragma unroll
    for (int q = 0; q < 4; ++q) {
      float4 f = *(const float4*)(src + q * 4);
      T[n][c + q * 4 + 0] = f2bf(f.x);
      T[n][c + q * 4 + 1] = f2bf(f.y);
      T[n][c + q * 4 + 2] = f2bf(f.z);
      T[n][c + q * 4 + 3] = f2bf(f.w);
    }
    __syncthreads();
    int d = tid >> 2, nc = (tid & 3) * 16;
    union { bf16x8 v; ushort h[8]; } o0, o1;
#pragma unroll
    for (int i = 0; i < 8; ++i) { o0.h[i] = T[nc + i][d]; o1.h[i] = T[nc + 8 + i][d]; }
    __hip_bfloat16* dst = HT + ((size_t)b * ND + d0 + d) * NN + n0 + nc;
    *(bf16x8*)(void*)dst = o0.v;
    *(bf16x8*)(void*)(dst + 8) = o1.v;
  }
}

// =====================================================================
// K2: M = rdeg ⊙ (A·H) via C = Ab · HT^T, 32x32 tile per wave,
// fused deterministic m2 partials (per col-tile ct).
// =====================================================================
__global__ __launch_bounds__(256) void k_gemmM(const __hip_bfloat16* __restrict__ Ab,
                                               const __hip_bfloat16* __restrict__ HT,
                                               const float* __restrict__ rdeg,
                                               __hip_bfloat16* __restrict__ Mb,
                                               float* __restrict__ m2p) {
  int wave = threadIdx.x >> 6, lane = threadIdx.x & 63;
  int b = blockIdx.x & 7, t = blockIdx.x >> 3;   // t in [0,32)
  int tile = t * 4 + wave;                       // [0,128)
  int rt = tile >> 3, ct = tile & 7;
  int r0 = rt * 32, c0 = ct * 32;
  int rl = lane & 15, g4 = lane >> 4;
  const __hip_bfloat16* X = Ab + (size_t)b * NN * NN;
  const __hip_bfloat16* Y = HT + (size_t)b * ND * NN;
  f32x4 acc[2][2];
#pragma unroll
  for (int i = 0; i < 2; ++i)
#pragma unroll
    for (int j = 0; j < 2; ++j) { acc[i][j][0] = 0.f; acc[i][j][1] = 0.f; acc[i][j][2] = 0.f; acc[i][j][3] = 0.f; }
#pragma unroll
  for (int kk = 0; kk < NN / 32; ++kk) {
    int kb = kk * 32 + g4 * 8;
    bf16x8 a[2], bv[2];
#pragma unroll
    for (int i = 0; i < 2; ++i)
      a[i] = *(const bf16x8*)(const void*)(X + (size_t)(r0 + i * 16 + rl) * NN + kb);
#pragma unroll
    for (int j = 0; j < 2; ++j)
      bv[j] = *(const bf16x8*)(const void*)(Y + (size_t)(c0 + j * 16 + rl) * NN + kb);
#pragma unroll
    for (int i = 0; i < 2; ++i)
#pragma unroll
      for (int j = 0; j < 2; ++j)
        acc[i][j] = __builtin_amdgcn_mfma_f32_16x16x32_bf16(a[i], bv[j], acc[i][j], 0, 0, 0);
  }
#pragma unroll
  for (int i = 0; i < 2; ++i)
#pragma unroll
    for (int r = 0; r < 4; ++r) {
      int row = r0 + i * 16 + g4 * 4 + r;
      float rd = rdeg[b * NN + row];
      float ss = 0.f;
#pragma unroll
      for (int j = 0; j < 2; ++j) {
        float m = rd * acc[i][j][r];
        int col = c0 + j * 16 + rl;
        Mb[((size_t)b * NN + row) * ND + col] = __float2bfloat16(m);
        ss += m * m;
      }
      ss = wred16(ss);
      if (rl == 0) m2p[(size_t)ct * (NB * NN) + b * NN + row] = ss;
    }
}

// =====================================================================
// K3: fused gaussian + gram + output.
// Block = (b, 64x64 tile, head-group hg of 8 heads).
// Phase 1: waves cooperatively compute G tile -> LDS (exp applied).
// Phase 2: each wave computes Gram for 2 heads, adds LDS G, writes out.
// =====================================================================
__global__ __launch_bounds__(256) void k_out(const __hip_bfloat16* __restrict__ Hb,
                                             const __hip_bfloat16* __restrict__ Mb,
                                             const __hip_bfloat16* __restrict__ spb,
                                             const float* __restrict__ h2,
                                             const float* __restrict__ m2p,
                                             const float* __restrict__ sigma,
                                             float* __restrict__ out) {
  __shared__ float Gt[64][66];
  __shared__ float h2s[64], m2s[64];
  int b = blockIdx.x & 7;
  int t2 = blockIdx.x >> 3;                 // [0,128)
  int ct = t2 & 7, rt = (t2 >> 3) & 7, hg = t2 >> 6;
  int r0 = rt * 64, c0 = ct * 64;
  int tid = threadIdx.x;
  int wave = tid >> 6, lane = tid & 63;
  int rl = lane & 15, g4 = lane >> 4;

  if (tid < 64) {
    h2s[tid] = h2[b * NN + r0 + tid];
  } else if (tid < 128) {
    int c = tid - 64;
    float s = 0.f;
#pragma unroll
    for (int p = 0; p < 8; ++p) s += m2p[(size_t)p * (NB * NN) + b * NN + c0 + c];
    m2s[c] = s;
  }
  __syncthreads();

  // ---- phase 1: G rows [wave*16, wave*16+16)
  {
    const __hip_bfloat16* X = Hb + (size_t)b * NN * ND;
    const __hip_bfloat16* Y = Mb + (size_t)b * NN * ND;
    int rbase = r0 + wave * 16;
    f32x4 acc[4];
#pragma unroll
    for (int j = 0; j < 4; ++j) { acc[j][0] = 0.f; acc[j][1] = 0.f; acc[j][2] = 0.f; acc[j][3] = 0.f; }
#pragma unroll
    for (int kk = 0; kk < ND / 32; ++kk) {
      int kb = kk * 32 + g4 * 8;
      bf16x8 a = *(const bf16x8*)(const void*)(X + (size_t)(rbase + rl) * ND + kb);
#pragma unroll
      for (int j = 0; j < 4; ++j) {
        bf16x8 bv = *(const bf16x8*)(const void*)(Y + (size_t)(c0 + j * 16 + rl) * ND + kb);
        acc[j] = __builtin_amdgcn_mfma_f32_16x16x32_bf16(a, bv, acc[j], 0, 0, 0);
      }
    }
    float sg = sigma[0];
    float inv = 0.5f / (sg * sg);
#pragma unroll
    for (int j = 0; j < 4; ++j)
#pragma unroll
      for (int r = 0; r < 4; ++r) {
        int rowl = wave * 16 + g4 * 4 + r;
        int col = j * 16 + rl;
        float d2 = h2s[rowl] + m2s[col] - 2.0f * acc[j][r];
        Gt[rowl][col] = __expf(-d2 * inv);
      }
  }
  __syncthreads();

  // ---- phase 2: 2 heads per wave
#pragma unroll
  for (int hh = 0; hh < 2; ++hh) {
    int h = hg * 8 + wave * 2 + hh;
    const __hip_bfloat16* X = spb + ((size_t)b * NH + h) * NN * NS;
    f32x4 acc[4][4];
#pragma unroll
    for (int i = 0; i < 4; ++i)
#pragma unroll
      for (int j = 0; j < 4; ++j) { acc[i][j][0] = 0.f; acc[i][j][1] = 0.f; acc[i][j][2] = 0.f; acc[i][j][3] = 0.f; }
#pragma unroll
    for (int kk = 0; kk < NS / 32; ++kk) {
      int kb = kk * 32 + g4 * 8;
      bf16x8 a[4], bv[4];
#pragma unroll
      for (int i = 0; i < 4; ++i)
        a[i] = *(const bf16x8*)(const void*)(X + (size_t)(r0 + i * 16 + rl) * NS + kb);
#pragma unroll
      for (int j = 0; j < 4; ++j)
        bv[j] = *(const bf16x8*)(const void*)(X + (size_t)(c0 + j * 16 + rl) * NS + kb);
#pragma unroll
      for (int i = 0; i < 4; ++i)
#pragma unroll
        for (int j = 0; j < 4; ++j)
          acc[i][j] = __builtin_amdgcn_mfma_f32_16x16x32_bf16(a[i], bv[j], acc[i][j], 0, 0, 0);
    }
    float* ob = out + ((size_t)b * NH + h) * NN * NN;
#pragma unroll
    for (int i = 0; i < 4; ++i)
#pragma unroll
      for (int j = 0; j < 4; ++j)
#pragma unroll
        for (int r = 0; r < 4; ++r) {
          int rowl = i * 16 + g4 * 4 + r;
          int col = j * 16 + rl;
          ob[(size_t)(r0 + rowl) * NN + c0 + col] = acc[i][j][r] + Gt[rowl][col];
        }
  }
}

extern "C" void kernel_launch(void* const* d_in, const int* in_sizes, int n_in,
                              void* d_out, int out_size, void* d_ws, size_t ws_size,
                              hipStream_t stream) {
  const int* pos = (const int*)d_in[0];
  const float* H = (const float*)d_in[1];
  const float* A = (const float*)d_in[2];
  const float* sigma = (const float*)d_in[3];
  const float* emb = (const float*)d_in[4];
  // d_in[5] (vt_weight) only affects the sliced-off padded row/col -> unused.
  float* out = (float*)d_out;

  char* ws = (char*)d_ws;
  size_t off = 0;
  auto alloc = [&](size_t bytes) -> void* {
    void* p = ws + off;
    off = (off + bytes + 255) & ~(size_t)255;
    return p;
  };
  __hip_bfloat16* spb = (__hip_bfloat16*)alloc((size_t)NB * NH * NN * NS * 2);
  __hip_bfloat16* Ab  = (__hip_bfloat16*)alloc((size_t)NB * NN * NN * 2);
  __hip_bfloat16* Hb  = (__hip_bfloat16*)alloc((size_t)NB * NN * ND * 2);
  __hip_bfloat16* HT  = (__hip_bfloat16*)alloc((size_t)NB * ND * NN * 2);
  __hip_bfloat16* Mb  = (__hip_bfloat16*)alloc((size_t)NB * NN * ND * 2);
  float* m2p  = (float*)alloc((size_t)8 * NB * NN * 4);
  float* rdeg = (float*)alloc((size_t)NB * NN * 4);
  float* h2   = (float*)alloc((size_t)NB * NN * 4);

  k_prep<<<3328, 256, 0, stream>>>(pos, emb, H, A, spb, Ab, Hb, HT, rdeg, h2);
  k_gemmM<<<256, 256, 0, stream>>>(Ab, HT, rdeg, Mb, m2p);
  k_out<<<1024, 256, 0, stream>>>(Hb, Mb, spb, h2, m2p, sigma, out);
}